// Round 1
// baseline (702.312 us; speedup 1.0000x reference)
//
#include <hip/hip_runtime.h>
#include <hip/hip_bf16.h>

// LightGCN forward: x0 = concat(user_emb, item_emb); 3x { x = A*x; acc += x }; out = acc/4.
// A given as sorted COO (rows sorted) -> treat as CSR via binary-searched row_ptr.
// One 64-lane wave per output row; lane = embedding dim (EMB=64). No atomics.

#define EMB 64

__global__ void init_x_kernel(const float4* __restrict__ user,
                              const float4* __restrict__ item,
                              float4* __restrict__ x,
                              float4* __restrict__ acc,
                              int n_user_vec, int n_total_vec) {
    int i = blockIdx.x * blockDim.x + threadIdx.x;
    if (i >= n_total_vec) return;
    float4 v = (i < n_user_vec) ? user[i] : item[i - n_user_vec];
    x[i] = v;
    acc[i] = v;
}

// row_ptr[r] = lower_bound(rows, r); rows are sorted. r in [0, n_rows].
__global__ void build_row_ptr_kernel(const int* __restrict__ rows, int nnz,
                                     int n_rows, int* __restrict__ row_ptr) {
    int r = blockIdx.x * blockDim.x + threadIdx.x;
    if (r > n_rows) return;
    int lo = 0, hi = nnz;
    while (lo < hi) {
        int mid = (lo + hi) >> 1;
        if (rows[mid] < r) lo = mid + 1; else hi = mid;
    }
    row_ptr[r] = lo;
}

// One wave per row. lane d accumulates sum_e vals[e] * x[cols[e]*64 + d].
// Fused epilogue: y[row] = a; acc[row] = (acc[row] + a) * scale.
__global__ void spmm_kernel(const int* __restrict__ row_ptr,
                            const int* __restrict__ cols,
                            const float* __restrict__ vals,
                            const float* __restrict__ x,
                            float* __restrict__ y,
                            float* __restrict__ acc,
                            float scale, int n_rows) {
    int wid  = (blockIdx.x * blockDim.x + threadIdx.x) >> 6;
    int lane = threadIdx.x & 63;
    if (wid >= n_rows) return;

    int start = row_ptr[wid];
    int end   = row_ptr[wid + 1];

    float a = 0.0f;
    for (int base = start; base < end; base += 64) {
        int e = base + lane;
        int   c = 0;
        float v = 0.0f;
        if (e < end) { c = cols[e]; v = vals[e]; }
        int len = end - base;
        if (len > 64) len = 64;
        for (int j = 0; j < len; ++j) {
            int   cj = __shfl(c, j);
            float vj = __shfl(v, j);
            a += vj * x[(size_t)cj * EMB + lane];
        }
    }

    size_t o = (size_t)wid * EMB + lane;
    y[o] = a;
    acc[o] = (acc[o] + a) * scale;
}

extern "C" void kernel_launch(void* const* d_in, const int* in_sizes, int n_in,
                              void* d_out, int out_size, void* d_ws, size_t ws_size,
                              hipStream_t stream) {
    const float* user_emb = (const float*)d_in[0];
    const float* item_emb = (const float*)d_in[1];
    const int*   adj_rows = (const int*)d_in[2];
    const int*   adj_cols = (const int*)d_in[3];
    const float* adj_vals = (const float*)d_in[4];

    const int n_users = in_sizes[0] / EMB;
    const int n_items = in_sizes[1] / EMB;
    const int nnz     = in_sizes[2];
    const int n       = n_users + n_items;

    float* acc = (float*)d_out;

    char* ws = (char*)d_ws;
    size_t xbytes = (size_t)n * EMB * sizeof(float);
    float* xA = (float*)ws;
    float* xB = (float*)(ws + xbytes);
    int* row_ptr = (int*)(ws + 2 * xbytes);

    // init: x0 = concat(user, item); acc = x0
    int nvec = n * (EMB / 4);
    init_x_kernel<<<(nvec + 255) / 256, 256, 0, stream>>>(
        (const float4*)user_emb, (const float4*)item_emb,
        (float4*)xA, (float4*)acc, n_users * (EMB / 4), nvec);

    // CSR row pointers from sorted rows
    build_row_ptr_kernel<<<(n + 1 + 255) / 256, 256, 0, stream>>>(
        adj_rows, nnz, n, row_ptr);

    // 3 propagation layers, ping-pong x buffers; final layer fuses /4
    dim3 grid(((size_t)n * 64 + 255) / 256);
    float* xc = xA;
    float* xn = xB;
    for (int l = 0; l < 3; ++l) {
        float scale = (l == 2) ? 0.25f : 1.0f;
        spmm_kernel<<<grid, 256, 0, stream>>>(
            row_ptr, adj_cols, adj_vals, xc, xn, acc, scale, n);
        float* t = xc; xc = xn; xn = t;
    }
}

// Round 2
// 460.187 us; speedup vs baseline: 1.5261x; 1.5261x over previous
//
#include <hip/hip_runtime.h>
#include <hip/hip_bf16.h>

// LightGCN forward: x0 = concat(user_emb, item_emb); 3x { x = A*x; acc += x }; out = acc/4.
// A given as sorted COO (rows sorted) -> CSR via binary-searched row_ptr.
// One 64-lane wave per output row; lane = embedding dim (EMB=64). No atomics.
// Gather loads batched 8-wide for latency hiding.

#define EMB 64

__global__ void init_x_kernel(const float4* __restrict__ user,
                              const float4* __restrict__ item,
                              float4* __restrict__ x,
                              float4* __restrict__ acc,
                              int n_user_vec, int n_total_vec) {
    int i = blockIdx.x * blockDim.x + threadIdx.x;
    if (i >= n_total_vec) return;
    float4 v = (i < n_user_vec) ? user[i] : item[i - n_user_vec];
    x[i] = v;
    acc[i] = v;
}

// row_ptr[r] = lower_bound(rows, r); rows are sorted. r in [0, n_rows].
__global__ void build_row_ptr_kernel(const int* __restrict__ rows, int nnz,
                                     int n_rows, int* __restrict__ row_ptr) {
    int r = blockIdx.x * blockDim.x + threadIdx.x;
    if (r > n_rows) return;
    int lo = 0, hi = nnz;
    while (lo < hi) {
        int mid = (lo + hi) >> 1;
        if (rows[mid] < r) lo = mid + 1; else hi = mid;
    }
    row_ptr[r] = lo;
}

// One wave per row. lane d accumulates sum_e vals[e] * x[cols[e]*64 + d].
// write_y: store y[row] = a (skipped on last layer).
// Epilogue: acc[row] = (acc[row] + a) * scale.
__global__ void spmm_kernel(const int* __restrict__ row_ptr,
                            const int* __restrict__ cols,
                            const float* __restrict__ vals,
                            const float* __restrict__ x,
                            float* __restrict__ y,
                            float* __restrict__ acc,
                            float scale, int write_y, int n_rows) {
    int wid  = (blockIdx.x * blockDim.x + threadIdx.x) >> 6;
    int lane = threadIdx.x & 63;
    if (wid >= n_rows) return;

    int start = row_ptr[wid];
    int end   = row_ptr[wid + 1];

    float a = 0.0f;
    for (int base = start; base < end; base += 64) {
        int e = base + lane;
        int   c = 0;
        float v = 0.0f;
        if (e < end) { c = cols[e]; v = vals[e]; }
        int len = end - base;
        if (len > 64) len = 64;

        // chunks of 8: issue 8 independent gathers, then 8 FMAs.
        // slots past len have v==0 (shfl from zeroed lanes) -> junk load of
        // x[0..] row, multiplied by 0. x[0] row stays L1-hot.
        for (int j = 0; j < len; j += 8) {
            float xv[8];
            float vj[8];
#pragma unroll
            for (int k = 0; k < 8; ++k) {
                int   cj = __shfl(c, j + k);
                vj[k]    = __shfl(v, j + k);
                xv[k]    = x[(size_t)cj * EMB + lane];
            }
#pragma unroll
            for (int k = 0; k < 8; ++k) a += vj[k] * xv[k];
        }
    }

    size_t o = (size_t)wid * EMB + lane;
    if (write_y) y[o] = a;
    acc[o] = (acc[o] + a) * scale;
}

extern "C" void kernel_launch(void* const* d_in, const int* in_sizes, int n_in,
                              void* d_out, int out_size, void* d_ws, size_t ws_size,
                              hipStream_t stream) {
    const float* user_emb = (const float*)d_in[0];
    const float* item_emb = (const float*)d_in[1];
    const int*   adj_rows = (const int*)d_in[2];
    const int*   adj_cols = (const int*)d_in[3];
    const float* adj_vals = (const float*)d_in[4];

    const int n_users = in_sizes[0] / EMB;
    const int n_items = in_sizes[1] / EMB;
    const int nnz     = in_sizes[2];
    const int n       = n_users + n_items;

    float* acc = (float*)d_out;

    char* ws = (char*)d_ws;
    size_t xbytes = (size_t)n * EMB * sizeof(float);
    float* xA = (float*)ws;
    float* xB = (float*)(ws + xbytes);
    int* row_ptr = (int*)(ws + 2 * xbytes);

    // init: x0 = concat(user, item); acc = x0
    int nvec = n * (EMB / 4);
    init_x_kernel<<<(nvec + 255) / 256, 256, 0, stream>>>(
        (const float4*)user_emb, (const float4*)item_emb,
        (float4*)xA, (float4*)acc, n_users * (EMB / 4), nvec);

    // CSR row pointers from sorted rows
    build_row_ptr_kernel<<<(n + 1 + 255) / 256, 256, 0, stream>>>(
        adj_rows, nnz, n, row_ptr);

    // 3 propagation layers, ping-pong x buffers; last layer skips y write
    // and fuses the /4.
    dim3 grid(((size_t)n * 64 + 255) / 256);
    float* xc = xA;
    float* xn = xB;
    for (int l = 0; l < 3; ++l) {
        float scale   = (l == 2) ? 0.25f : 1.0f;
        int   write_y = (l == 2) ? 0 : 1;
        spmm_kernel<<<grid, 256, 0, stream>>>(
            row_ptr, adj_cols, adj_vals, xc, xn, acc, scale, write_y, n);
        float* t = xc; xc = xn; xn = t;
    }
}